// Round 2
// baseline (394.372 us; speedup 1.0000x reference)
//
#include <hip/hip_runtime.h>
#include <math.h>

// PGTAttention fused block, MI355X gfx950. Round 2.
// Pipeline: cast/transpose prep -> bf16 MFMA GEMM (qkv, contiguous bf16 out) ->
//           V transpose -> flash attention (K staged/LDS-swizzled, V direct-from-L2,
//           defer-max, fused PMSNorm) -> bf16 MFMA GEMM (proj, fp32 out).
// MFMA 16x16x32 bf16 layouts (HW-verified):
//   A/B operand: lane holds row (lane&15), k = (lane>>4)*8 + j (contiguous 8)
//   C/D: col = lane&15, row = (lane>>4)*4 + reg

typedef unsigned short u16;
typedef unsigned int   u32;
typedef u16   u16x8 __attribute__((ext_vector_type(8)));
typedef __bf16 bf16x8 __attribute__((ext_vector_type(8)));
typedef float f32x4 __attribute__((ext_vector_type(4)));

#define GPTR(p) ((const __attribute__((address_space(1))) void*)(p))
#define LPTR(p) ((__attribute__((address_space(3))) void*)(p))

__device__ __forceinline__ u16 f2bf(float x) {
  u32 u = __float_as_uint(x);
  return (u16)((u + 0x7fffu + ((u >> 16) & 1u)) >> 16);  // RNE
}

__device__ __forceinline__ bf16x8 ld8(const void* p) {
  u16x8 v = *reinterpret_cast<const u16x8*>(p);
  return __builtin_bit_cast(bf16x8, v);
}

// global->LDS direct copy, 16B/lane; LDS dest = wave-uniform base + lane*16.
__device__ __forceinline__ void g2l16(const void* g, void* l) {
  __builtin_amdgcn_global_load_lds(GPTR(g), LPTR(l), 16, 0, 0);
}

// ---------------- elementwise cast f32 -> bf16, 8 elems/thread ----------------
__global__ void cast_bf16_kernel(const float* __restrict__ in, u16* __restrict__ out, int n8) {
  int i = blockIdx.x * 256 + threadIdx.x;
  if (i >= n8) return;
  const float4* p = reinterpret_cast<const float4*>(in) + (size_t)i * 2;
  float4 a = p[0], b = p[1];
  u16x8 v;
  v[0] = f2bf(a.x); v[1] = f2bf(a.y); v[2] = f2bf(a.z); v[3] = f2bf(a.w);
  v[4] = f2bf(b.x); v[5] = f2bf(b.y); v[6] = f2bf(b.z); v[7] = f2bf(b.w);
  reinterpret_cast<u16x8*>(out)[i] = v;
}

// ---------------- transpose + cast: out[c][r] = bf16(in[r][c]), in is R x C f32 -------
__global__ void tcast_kernel(const float* __restrict__ in, u16* __restrict__ out, int R, int C) {
  __shared__ float t[32][33];
  int bx = blockIdx.x * 32, by = blockIdx.y * 32;
  int x = threadIdx.x, y = threadIdx.y;  // (32, 8)
  #pragma unroll
  for (int k = 0; k < 32; k += 8)
    t[y + k][x] = in[(size_t)(by + y + k) * C + (bx + x)];
  __syncthreads();
  #pragma unroll
  for (int k = 0; k < 32; k += 8)
    out[(size_t)(bx + y + k) * R + (by + x)] = f2bf(t[x][y + k]);
}

// ------- V transpose from qkv: out[bh][d][s] = qkv[b][s][4096 + h*256 + d] ----------
__global__ void tv_kernel(const u16* __restrict__ qkv, u16* __restrict__ out) {
  __shared__ u16 t[32][33];
  int bh = blockIdx.z, b = bh >> 3, h = bh & 7;
  const u16* ip = qkv + (size_t)b * 2048 * 6144 + 4096 + h * 256;
  u16* op = out + (size_t)bh * 256 * 2048;
  int bx = blockIdx.x * 32, by = blockIdx.y * 32;  // bx: d, by: s
  int x = threadIdx.x, y = threadIdx.y;
  #pragma unroll
  for (int k = 0; k < 32; k += 8)
    t[y + k][x] = ip[(size_t)(by + y + k) * 6144 + (bx + x)];
  __syncthreads();
  #pragma unroll
  for (int k = 0; k < 32; k += 8)
    op[(size_t)(bx + y + k) * 2048 + (by + x)] = t[x][y + k];
}

// ---------------- GEMM: C[M,N] = A[M,K] * Bt[N,K]^T  (bf16 in, f32 acc) ----------------
// 128x128 tile, BK=64 (single 32KB buffer, 2 barriers per 64-K), 4 waves each 64x64.
// LDS rows 128B; XOR-swizzle byte ^= (row&7)<<4 on stage-source AND read (involution).
// Cf!=null: f32 out.  Cb: bf16 out (contiguous [M][N]).
__global__ __launch_bounds__(256) void gemm_bt_kernel(
    const u16* __restrict__ A, const u16* __restrict__ Bt,
    float* __restrict__ Cf, u16* __restrict__ Cb, int M, int N, int K) {
  __shared__ __align__(16) u16 sA[128 * 64];  // 16 KiB
  __shared__ __align__(16) u16 sB[128 * 64];  // 16 KiB
  const int tid = threadIdx.x;
  const int lane = tid & 63, w = tid >> 6;
  const int wr = w >> 1, wc = w & 1;
  const int g = lane >> 4, li = lane & 15;
  const int bn = blockIdx.x * 128, bm = blockIdx.y * 128;

  // hoisted staging pointers (advance 128B per K-step)
  const char* aSrc[4]; const char* bSrc[4];
  char* aDst[4]; char* bDst[4];
  #pragma unroll
  for (int j = 0; j < 4; ++j) {
    int chunk = w * 4 + j;            // 16 chunks of 1KB per matrix
    int o = chunk * 1024 + lane * 16;
    int row = o >> 7, cb = o & 127;
    int cbs = cb ^ ((row & 7) << 4);  // inverse-swizzled source
    aSrc[j] = (const char*)A + (size_t)(bm + row) * K * 2 + cbs;
    bSrc[j] = (const char*)Bt + (size_t)(bn + row) * K * 2 + cbs;
    aDst[j] = (char*)sA + chunk * 1024;
    bDst[j] = (char*)sB + chunk * 1024;
  }
  // hoisted fragment read addresses (loop-invariant)
  const char* aRd[2][4]; const char* bRd[2][4];
  #pragma unroll
  for (int ks = 0; ks < 2; ++ks) {
    #pragma unroll
    for (int f = 0; f < 4; ++f) {
      int ra = wr * 64 + f * 16 + li;
      aRd[ks][f] = (const char*)sA + ra * 128 + ((ks * 64 + g * 16) ^ ((ra & 7) << 4));
      int rb = wc * 64 + f * 16 + li;
      bRd[ks][f] = (const char*)sB + rb * 128 + ((ks * 64 + g * 16) ^ ((rb & 7) << 4));
    }
  }

  const f32x4 fz = {0.f, 0.f, 0.f, 0.f};
  f32x4 acc[4][4];
  #pragma unroll
  for (int i = 0; i < 4; ++i)
    #pragma unroll
    for (int j = 0; j < 4; ++j) acc[i][j] = fz;

  for (int k0 = 0; k0 < K; k0 += 64) {
    #pragma unroll
    for (int j = 0; j < 4; ++j) { g2l16(aSrc[j], aDst[j]); g2l16(bSrc[j], bDst[j]); }
    #pragma unroll
    for (int j = 0; j < 4; ++j) { aSrc[j] += 128; bSrc[j] += 128; }
    __syncthreads();
    bf16x8 af[2][4], bfv[2][4];
    #pragma unroll
    for (int ks = 0; ks < 2; ++ks)
      #pragma unroll
      for (int f = 0; f < 4; ++f) { af[ks][f] = ld8(aRd[ks][f]); bfv[ks][f] = ld8(bRd[ks][f]); }
    #pragma unroll
    for (int ks = 0; ks < 2; ++ks)
      #pragma unroll
      for (int mf = 0; mf < 4; ++mf)
        #pragma unroll
        for (int nf = 0; nf < 4; ++nf)
          acc[mf][nf] = __builtin_amdgcn_mfma_f32_16x16x32_bf16(af[ks][mf], bfv[ks][nf], acc[mf][nf], 0, 0, 0);
    __syncthreads();
  }

  if (Cf) {
    #pragma unroll
    for (int mf = 0; mf < 4; ++mf)
      #pragma unroll
      for (int nf = 0; nf < 4; ++nf)
        #pragma unroll
        for (int r = 0; r < 4; ++r) {
          int gm = bm + wr * 64 + mf * 16 + g * 4 + r;
          int gn = bn + wc * 64 + nf * 16 + li;
          Cf[(size_t)gm * N + gn] = acc[mf][nf][r];
        }
  } else {
    #pragma unroll
    for (int mf = 0; mf < 4; ++mf)
      #pragma unroll
      for (int nf = 0; nf < 4; ++nf)
        #pragma unroll
        for (int r = 0; r < 4; ++r) {
          int gm = bm + wr * 64 + mf * 16 + g * 4 + r;
          int gn = bn + wc * 64 + nf * 16 + li;
          Cb[(size_t)gm * N + gn] = f2bf(acc[mf][nf][r]);
        }
  }
}

// ---------------- flash attention + fused PMSNorm ----------------
// 256 thr (4 waves), q-tile 64 (16 rows/wave), KV-tile 64. K staged via gload_lds with
// (row&7)<<4 swizzle (512B rows); V read direct from L2 (Vt [bh][d][s]); defer-max THR=8;
// stage-next issued right after the QK-read barrier so HBM latency hides under softmax+PV.
__global__ __launch_bounds__(256) void attn_kernel(
    const u16* __restrict__ qkv, const u16* __restrict__ Vt,
    const float* __restrict__ nw, u16* __restrict__ Mrg) {
  __shared__ __align__(16) u16 sK[64 * 256];      // 32 KiB
  __shared__ __align__(16) u16 sP[4 * 16 * 64];   //  8 KiB

  // causal load balance: pair q-tiles i and 31-i
  int flat = blockIdx.x;
  int u = flat & 255, pp = flat >> 8;
  int bh = u & 15, i0 = u >> 4;
  int qt = pp ? 31 - i0 : i0;
  int b = bh >> 3, h = bh & 7;

  const int tid = threadIdx.x, lane = tid & 63, w = tid >> 6;
  const int g = lane >> 4, li = lane & 15;
  const float NEG = -__builtin_inff();

  // hoist Q fragments
  int qrow = qt * 64 + w * 16 + li;
  const u16* qp = qkv + (size_t)(b * 2048 + qrow) * 6144 + h * 256;
  bf16x8 qf[8];
  #pragma unroll
  for (int c = 0; c < 8; ++c) qf[c] = ld8(qp + c * 32 + g * 8);

  // K staging pointers (advance 64 rows = 64*6144*2 B per tile)
  const char* kSrc[8]; char* kDst[8];
  #pragma unroll
  for (int it = 0; it < 8; ++it) {
    int o = it * 4096 + w * 1024 + lane * 16;
    int row = o >> 9, cb = o & 511;
    int cbs = cb ^ ((row & 7) << 4);
    kSrc[it] = (const char*)qkv + ((size_t)(b * 2048 + row) * 6144 + 2048 + h * 256) * 2 + cbs;
    kDst[it] = (char*)sK + it * 4096 + w * 1024;
  }
  const u16* vp = Vt + (size_t)bh * 256 * 2048;

  const f32x4 fz = {0.f, 0.f, 0.f, 0.f};
  f32x4 o[16];
  #pragma unroll
  for (int nf = 0; nf < 16; ++nf) o[nf] = fz;
  float m_[4] = {NEG, NEG, NEG, NEG};
  float l_[4] = {0.f, 0.f, 0.f, 0.f};

  // prologue: stage tile 0
  #pragma unroll
  for (int it = 0; it < 8; ++it) { g2l16(kSrc[it], kDst[it]); kSrc[it] += (size_t)64 * 6144 * 2; }

  for (int kt = 0; kt <= qt; ++kt) {
    __syncthreads();  // stage landed (drains vmcnt) + all waves aligned

    // S = Q * K^T : 4 col-fragments of 16
    f32x4 sacc[4] = {fz, fz, fz, fz};
    __builtin_amdgcn_s_setprio(1);
    #pragma unroll
    for (int nf = 0; nf < 4; ++nf) {
      int row = nf * 16 + li;
      int swz = (row & 7) << 4;
      const char* kr = (const char*)sK + row * 512;
      #pragma unroll
      for (int c = 0; c < 8; ++c)
        sacc[nf] = __builtin_amdgcn_mfma_f32_16x16x32_bf16(qf[c], ld8(kr + ((c * 64 + g * 16) ^ swz)), sacc[nf], 0, 0, 0);
    }
    __builtin_amdgcn_s_setprio(0);
    __syncthreads();  // all QK reads of sK done

    // issue next tile's staging now: lands during softmax+PV
    if (kt < qt) {
      #pragma unroll
      for (int it = 0; it < 8; ++it) { g2l16(kSrc[it], kDst[it]); kSrc[it] += (size_t)64 * 6144 * 2; }
    }

    // online softmax with defer-max (THR=8)
    const float isc = 1.0f / 64.0f;  // sqrt(256) * (LAYER_IDX+1)
    bool diag = (kt == qt);
    float p[4][4], mx[4];
    #pragma unroll
    for (int r = 0; r < 4; ++r) {
      int qr = qt * 64 + w * 16 + g * 4 + r;
      float m0 = NEG;
      #pragma unroll
      for (int nf = 0; nf < 4; ++nf) {
        float x = sacc[nf][r] * isc;
        if (diag) { int col = kt * 64 + nf * 16 + li; if (col > qr) x = NEG; }
        p[nf][r] = x;
        m0 = fmaxf(m0, x);
      }
      m0 = fmaxf(m0, __shfl_xor(m0, 1));
      m0 = fmaxf(m0, __shfl_xor(m0, 2));
      m0 = fmaxf(m0, __shfl_xor(m0, 4));
      m0 = fmaxf(m0, __shfl_xor(m0, 8));
      mx[r] = m0;
    }
    bool need = (mx[0] > m_[0] + 8.f) || (mx[1] > m_[1] + 8.f) ||
                (mx[2] > m_[2] + 8.f) || (mx[3] > m_[3] + 8.f);
    if (__any(need)) {
      #pragma unroll
      for (int r = 0; r < 4; ++r) {
        float mn = fmaxf(m_[r], mx[r]);
        float sc = __expf(m_[r] - mn);
        l_[r] *= sc; m_[r] = mn;
        #pragma unroll
        for (int nf = 0; nf < 16; ++nf) o[nf][r] *= sc;
      }
    }
    #pragma unroll
    for (int r = 0; r < 4; ++r) {
      float rs = 0.f;
      #pragma unroll
      for (int nf = 0; nf < 4; ++nf) {
        float e = __expf(p[nf][r] - m_[r]);
        p[nf][r] = e;
        rs += e;
      }
      rs += __shfl_xor(rs, 1);
      rs += __shfl_xor(rs, 2);
      rs += __shfl_xor(rs, 4);
      rs += __shfl_xor(rs, 8);
      l_[r] += rs;
    }

    // P -> per-wave swizzled LDS (rows 128B, swz (row&7)<<4)
    #pragma unroll
    for (int r = 0; r < 4; ++r) {
      int row = g * 4 + r;
      int swz = (row & 7) << 4;
      #pragma unroll
      for (int nf = 0; nf < 4; ++nf)
        *(u16*)((char*)sP + w * 2048 + row * 128 + (((nf * 16 + li) * 2) ^ swz)) = f2bf(p[nf][r]);
    }
    asm volatile("s_waitcnt lgkmcnt(0)" ::: "memory");  // wave-local write->read fence
    __builtin_amdgcn_sched_barrier(0);

    // O += P * V   (V direct from global/L2, Vt rows are d, k-contiguous in s)
    __builtin_amdgcn_s_setprio(1);
    #pragma unroll
    for (int ks = 0; ks < 2; ++ks) {
      bf16x8 pa = ld8((const char*)sP + w * 2048 + li * 128 + ((ks * 64 + g * 16) ^ ((li & 7) << 4)));
      #pragma unroll
      for (int nf = 0; nf < 16; ++nf) {
        bf16x8 vf = ld8(vp + (size_t)(nf * 16 + li) * 2048 + kt * 64 + ks * 32 + g * 8);
        o[nf] = __builtin_amdgcn_mfma_f32_16x16x32_bf16(pa, vf, o[nf], 0, 0, 0);
      }
    }
    __builtin_amdgcn_s_setprio(0);
  }

  // epilogue: 1/l, PMSNorm over d=256, *norm_weight, write merged [b][s][h*256+d] bf16
  #pragma unroll
  for (int r = 0; r < 4; ++r) {
    float inv_l = 1.0f / l_[r];
    float ss = 0.f;
    #pragma unroll
    for (int nf = 0; nf < 16; ++nf) {
      float v = o[nf][r] * inv_l;
      ss += v * v;
    }
    ss += __shfl_xor(ss, 1);
    ss += __shfl_xor(ss, 2);
    ss += __shfl_xor(ss, 4);
    ss += __shfl_xor(ss, 8);
    float rms = rsqrtf(ss * (1.0f / 256.0f) + 1e-5f);
    int row = qt * 64 + w * 16 + g * 4 + r;
    #pragma unroll
    for (int nf = 0; nf < 16; ++nf) {
      int d = nf * 16 + li;
      float v = o[nf][r] * inv_l * rms * nw[d];
      Mrg[((size_t)(b * 2048 + row)) * 2048 + h * 256 + d] = f2bf(v);
    }
  }
}

extern "C" void kernel_launch(void* const* d_in, const int* in_sizes, int n_in,
                              void* d_out, int out_size, void* d_ws, size_t ws_size,
                              hipStream_t stream) {
  const float* hs  = (const float*)d_in[0];   // [2,2048,2048]
  const float* wat = (const float*)d_in[1];   // [2048,6144]
  const float* wpr = (const float*)d_in[2];   // [2048,2048]
  const float* nw  = (const float*)d_in[3];   // [256]
  float* out = (float*)d_out;                 // [2,2048,2048] f32

  // workspace (88 MiB): Xb | Wp_t | Qkv | Vt ; Mrg aliases Xb (dead after GEMM1);
  // Wa_t scratch lives in d_out (fully overwritten by the final GEMM).
  char* ws = (char*)d_ws;
  u16* Xb   = (u16*)(ws + 0);                    // 16 MiB  [4096][2048] bf16
  u16* Wp_t = (u16*)(ws + (16u << 20));          //  8 MiB  [2048][2048] bf16 (w_proj^T)
  u16* Qkv  = (u16*)(ws + (24u << 20));          // 48 MiB  [4096][6144] bf16
  u16* Vt   = (u16*)(ws + (72u << 20));          // 16 MiB  [16][256][2048] bf16
  u16* Mrg  = Xb;
  u16* Wa_t = (u16*)d_out;                       // 24 MiB scratch (w_attn^T [6144][2048])

  dim3 t328(32, 8);
  cast_bf16_kernel<<<4096, 256, 0, stream>>>(hs, Xb, 1048576);
  tcast_kernel<<<dim3(192, 64), t328, 0, stream>>>(wat, Wa_t, 2048, 6144);
  tcast_kernel<<<dim3(64, 64), t328, 0, stream>>>(wpr, Wp_t, 2048, 2048);
  gemm_bt_kernel<<<dim3(48, 32), 256, 0, stream>>>(Xb, Wa_t, nullptr, Qkv, 4096, 6144, 2048);
  tv_kernel<<<dim3(8, 64, 16), t328, 0, stream>>>(Qkv, Vt);
  attn_kernel<<<512, 256, 0, stream>>>(Qkv, Vt, nw, Mrg);
  gemm_bt_kernel<<<dim3(16, 32), 256, 0, stream>>>(Mrg, Wp_t, out, nullptr, 4096, 2048, 2048);
  (void)in_sizes; (void)n_in; (void)out_size; (void)ws_size;
}

// Round 3
// 346.909 us; speedup vs baseline: 1.1368x; 1.1368x over previous
//
#include <hip/hip_runtime.h>
#include <math.h>

// PGTAttention fused block, MI355X gfx950. Round 3.
// Change vs r2: attention rebuilt — V re-staged in LDS (r2's direct-from-L2 V reads
// had 4KB lane stride = 64 cache lines/inst, latency-bound at 6% MfmaUtil), K double-
// buffered with counted-vmcnt raw-barrier pipeline (prefetch stays in flight across
// barriers, T3/T4-lite). GEMMs unchanged from r2.

typedef unsigned short u16;
typedef unsigned int   u32;
typedef u16   u16x8 __attribute__((ext_vector_type(8)));
typedef __bf16 bf16x8 __attribute__((ext_vector_type(8)));
typedef float f32x4 __attribute__((ext_vector_type(4)));

#define GPTR(p) ((const __attribute__((address_space(1))) void*)(p))
#define LPTR(p) ((__attribute__((address_space(3))) void*)(p))

__device__ __forceinline__ u16 f2bf(float x) {
  u32 u = __float_as_uint(x);
  return (u16)((u + 0x7fffu + ((u >> 16) & 1u)) >> 16);  // RNE
}

__device__ __forceinline__ bf16x8 ld8(const void* p) {
  u16x8 v = *reinterpret_cast<const u16x8*>(p);
  return __builtin_bit_cast(bf16x8, v);
}

// global->LDS direct copy, 16B/lane; LDS dest = wave-uniform base + lane*16.
__device__ __forceinline__ void g2l16(const void* g, void* l) {
  __builtin_amdgcn_global_load_lds(GPTR(g), LPTR(l), 16, 0, 0);
}

// ---------------- elementwise cast f32 -> bf16, 8 elems/thread ----------------
__global__ void cast_bf16_kernel(const float* __restrict__ in, u16* __restrict__ out, int n8) {
  int i = blockIdx.x * 256 + threadIdx.x;
  if (i >= n8) return;
  const float4* p = reinterpret_cast<const float4*>(in) + (size_t)i * 2;
  float4 a = p[0], b = p[1];
  u16x8 v;
  v[0] = f2bf(a.x); v[1] = f2bf(a.y); v[2] = f2bf(a.z); v[3] = f2bf(a.w);
  v[4] = f2bf(b.x); v[5] = f2bf(b.y); v[6] = f2bf(b.z); v[7] = f2bf(b.w);
  reinterpret_cast<u16x8*>(out)[i] = v;
}

// ---------------- transpose + cast: out[c][r] = bf16(in[r][c]), in is R x C f32 -------
__global__ void tcast_kernel(const float* __restrict__ in, u16* __restrict__ out, int R, int C) {
  __shared__ float t[32][33];
  int bx = blockIdx.x * 32, by = blockIdx.y * 32;
  int x = threadIdx.x, y = threadIdx.y;  // (32, 8)
  #pragma unroll
  for (int k = 0; k < 32; k += 8)
    t[y + k][x] = in[(size_t)(by + y + k) * C + (bx + x)];
  __syncthreads();
  #pragma unroll
  for (int k = 0; k < 32; k += 8)
    out[(size_t)(bx + y + k) * R + (by + x)] = f2bf(t[x][y + k]);
}

// ------- V transpose from qkv: out[bh][d][s] = qkv[b][s][4096 + h*256 + d] ----------
__global__ void tv_kernel(const u16* __restrict__ qkv, u16* __restrict__ out) {
  __shared__ u16 t[32][33];
  int bh = blockIdx.z, b = bh >> 3, h = bh & 7;
  const u16* ip = qkv + (size_t)b * 2048 * 6144 + 4096 + h * 256;
  u16* op = out + (size_t)bh * 256 * 2048;
  int bx = blockIdx.x * 32, by = blockIdx.y * 32;  // bx: d, by: s
  int x = threadIdx.x, y = threadIdx.y;
  #pragma unroll
  for (int k = 0; k < 32; k += 8)
    t[y + k][x] = ip[(size_t)(by + y + k) * 6144 + (bx + x)];
  __syncthreads();
  #pragma unroll
  for (int k = 0; k < 32; k += 8)
    op[(size_t)(bx + y + k) * 2048 + (by + x)] = t[x][y + k];
}

// ---------------- GEMM: C[M,N] = A[M,K] * Bt[N,K]^T  (bf16 in, f32 acc) ----------------
// 128x128 tile, BK=64 (single 32KB buffer), 4 waves each 64x64. Unchanged from r2.
__global__ __launch_bounds__(256) void gemm_bt_kernel(
    const u16* __restrict__ A, const u16* __restrict__ Bt,
    float* __restrict__ Cf, u16* __restrict__ Cb, int M, int N, int K) {
  __shared__ __align__(16) u16 sA[128 * 64];  // 16 KiB
  __shared__ __align__(16) u16 sB[128 * 64];  // 16 KiB
  const int tid = threadIdx.x;
  const int lane = tid & 63, w = tid >> 6;
  const int wr = w >> 1, wc = w & 1;
  const int g = lane >> 4, li = lane & 15;
  const int bn = blockIdx.x * 128, bm = blockIdx.y * 128;

  const char* aSrc[4]; const char* bSrc[4];
  char* aDst[4]; char* bDst[4];
  #pragma unroll
  for (int j = 0; j < 4; ++j) {
    int chunk = w * 4 + j;
    int o = chunk * 1024 + lane * 16;
    int row = o >> 7, cb = o & 127;
    int cbs = cb ^ ((row & 7) << 4);
    aSrc[j] = (const char*)A + (size_t)(bm + row) * K * 2 + cbs;
    bSrc[j] = (const char*)Bt + (size_t)(bn + row) * K * 2 + cbs;
    aDst[j] = (char*)sA + chunk * 1024;
    bDst[j] = (char*)sB + chunk * 1024;
  }
  const char* aRd[2][4]; const char* bRd[2][4];
  #pragma unroll
  for (int ks = 0; ks < 2; ++ks) {
    #pragma unroll
    for (int f = 0; f < 4; ++f) {
      int ra = wr * 64 + f * 16 + li;
      aRd[ks][f] = (const char*)sA + ra * 128 + ((ks * 64 + g * 16) ^ ((ra & 7) << 4));
      int rb = wc * 64 + f * 16 + li;
      bRd[ks][f] = (const char*)sB + rb * 128 + ((ks * 64 + g * 16) ^ ((rb & 7) << 4));
    }
  }

  const f32x4 fz = {0.f, 0.f, 0.f, 0.f};
  f32x4 acc[4][4];
  #pragma unroll
  for (int i = 0; i < 4; ++i)
    #pragma unroll
    for (int j = 0; j < 4; ++j) acc[i][j] = fz;

  for (int k0 = 0; k0 < K; k0 += 64) {
    #pragma unroll
    for (int j = 0; j < 4; ++j) { g2l16(aSrc[j], aDst[j]); g2l16(bSrc[j], bDst[j]); }
    #pragma unroll
    for (int j = 0; j < 4; ++j) { aSrc[j] += 128; bSrc[j] += 128; }
    __syncthreads();
    bf16x8 af[2][4], bfv[2][4];
    #pragma unroll
    for (int ks = 0; ks < 2; ++ks)
      #pragma unroll
      for (int f = 0; f < 4; ++f) { af[ks][f] = ld8(aRd[ks][f]); bfv[ks][f] = ld8(bRd[ks][f]); }
    #pragma unroll
    for (int ks = 0; ks < 2; ++ks)
      #pragma unroll
      for (int mf = 0; mf < 4; ++mf)
        #pragma unroll
        for (int nf = 0; nf < 4; ++nf)
          acc[mf][nf] = __builtin_amdgcn_mfma_f32_16x16x32_bf16(af[ks][mf], bfv[ks][nf], acc[mf][nf], 0, 0, 0);
    __syncthreads();
  }

  if (Cf) {
    #pragma unroll
    for (int mf = 0; mf < 4; ++mf)
      #pragma unroll
      for (int nf = 0; nf < 4; ++nf)
        #pragma unroll
        for (int r = 0; r < 4; ++r) {
          int gm = bm + wr * 64 + mf * 16 + g * 4 + r;
          int gn = bn + wc * 64 + nf * 16 + li;
          Cf[(size_t)gm * N + gn] = acc[mf][nf][r];
        }
  } else {
    #pragma unroll
    for (int mf = 0; mf < 4; ++mf)
      #pragma unroll
      for (int nf = 0; nf < 4; ++nf)
        #pragma unroll
        for (int r = 0; r < 4; ++r) {
          int gm = bm + wr * 64 + mf * 16 + g * 4 + r;
          int gn = bn + wc * 64 + nf * 16 + li;
          Cb[(size_t)gm * N + gn] = f2bf(acc[mf][nf][r]);
        }
  }
}

// ---------------- flash attention + fused PMSNorm ----------------
// 256 thr (4 waves), q-tile 64 (16 rows/wave), KVBLK=32.
// sK double-buffered (2x16KB, swz (row&7)<<4), sV single (16KB, [256 d][32 s],
// swz (row&3)<<4), sP per-wave 16x32. Counted-vmcnt pipeline:
//   top: issue V(kt) [4/wave] + K(kt+1) [4/wave into alt buf]
//   QK(sK[cur]) -> softmax -> vmcnt(4) [V landed, K stays in flight] -> barrier
//   -> sP -> PV(sV,sP) -> barrier -> vmcnt(0) [K landed].
__global__ __launch_bounds__(256) void attn_kernel(
    const u16* __restrict__ qkv, const u16* __restrict__ Vt,
    const float* __restrict__ nw, u16* __restrict__ Mrg) {
  __shared__ __align__(16) u16 sK[2][32 * 256];   // 32 KiB
  __shared__ __align__(16) u16 sV[256 * 32];      // 16 KiB
  __shared__ __align__(16) u16 sP[4 * 16 * 32];   //  4 KiB

  // causal load balance: pair q-tiles i and 31-i
  int flat = blockIdx.x;
  int u = flat & 255, pp = flat >> 8;
  int bh = u & 15, i0 = u >> 4;
  int qt = pp ? 31 - i0 : i0;
  int b = bh >> 3, h = bh & 7;

  const int tid = threadIdx.x, lane = tid & 63, w = tid >> 6;
  const int g = lane >> 4, li = lane & 15;
  const float NEG = -__builtin_inff();

  // hoist Q fragments (16 rows/wave)
  int qrow = qt * 64 + w * 16 + li;
  const u16* qp = qkv + (size_t)(b * 2048 + qrow) * 6144 + h * 256;
  bf16x8 qf[8];
  #pragma unroll
  for (int c = 0; c < 8; ++c) qf[c] = ld8(qp + c * 32 + g * 8);

  // K staging: tile [32][256] = 16KB = 16 chunks, 4/wave; rows 512B, swz (row&7)<<4
  const size_t KADV = (size_t)32 * 6144 * 2;
  const char* kSrc[4]; u32 kDoff[4];
  #pragma unroll
  for (int j = 0; j < 4; ++j) {
    int chunk = w * 4 + j;
    int o = chunk * 1024 + lane * 16;
    int row = o >> 9, cb = o & 511;
    int cbs = cb ^ ((row & 7) << 4);
    kSrc[j] = (const char*)qkv + ((size_t)(b * 2048 + row) * 6144 + 2048 + h * 256) * 2 + cbs;
    kDoff[j] = chunk * 1024;
  }
  // V staging: tile [256 d][32 s] = 16KB, rows 64B, swz (row&3)<<4
  const char* vSrc[4]; char* vDst[4];
  #pragma unroll
  for (int j = 0; j < 4; ++j) {
    int chunk = w * 4 + j;
    int o = chunk * 1024 + lane * 16;
    int row = o >> 6, cb = o & 63;
    int cbs = cb ^ ((row & 3) << 4);
    vSrc[j] = (const char*)Vt + ((size_t)(bh * 256 + row) * 2048) * 2 + cbs;
    vDst[j] = (char*)sV + chunk * 1024;
  }

  const f32x4 fz = {0.f, 0.f, 0.f, 0.f};
  f32x4 o[16];
  #pragma unroll
  for (int nf = 0; nf < 16; ++nf) o[nf] = fz;
  float m_[4] = {NEG, NEG, NEG, NEG};
  float l_[4] = {0.f, 0.f, 0.f, 0.f};

  // prologue: stage K(0) into sK[0]
  #pragma unroll
  for (int j = 0; j < 4; ++j) { g2l16(kSrc[j], (char*)sK[0] + kDoff[j]); kSrc[j] += KADV; }
  asm volatile("s_waitcnt vmcnt(0)" ::: "memory");
  __syncthreads();

  int cur = 0;
  const int ktn = 2 * qt + 1;  // k-tiles of 32, cols up to 64*qt+63
  for (int kt = 0; kt <= ktn; ++kt) {
    const bool more = (kt < ktn);
    // issue V(kt) (sV free: post-PV barrier of prev iter) and K(kt+1) (alt buffer)
    #pragma unroll
    for (int j = 0; j < 4; ++j) { g2l16(vSrc[j], vDst[j]); vSrc[j] += 64; }
    if (more) {
      char* kb = (char*)sK[cur ^ 1];
      #pragma unroll
      for (int j = 0; j < 4; ++j) { g2l16(kSrc[j], kb + kDoff[j]); kSrc[j] += KADV; }
    }

    // S = Q * K^T from sK[cur] (landed: end-of-prev-iter vmcnt(0))
    f32x4 sacc[2] = {fz, fz};
    const char* kbase = (const char*)sK[cur];
    __builtin_amdgcn_s_setprio(1);
    #pragma unroll
    for (int nf = 0; nf < 2; ++nf) {
      int row = nf * 16 + li;
      int swz = (row & 7) << 4;
      const char* kr = kbase + row * 512;
      #pragma unroll
      for (int c = 0; c < 8; ++c)
        sacc[nf] = __builtin_amdgcn_mfma_f32_16x16x32_bf16(qf[c], ld8(kr + ((c * 64 + g * 16) ^ swz)), sacc[nf], 0, 0, 0);
    }
    __builtin_amdgcn_s_setprio(0);

    // online softmax with defer-max (THR=8); rows on (g,r), cols on li
    const float isc = 1.0f / 64.0f;  // sqrt(256) * (LAYER_IDX+1)
    const bool diag = (kt >= 2 * qt);
    float p[2][4], mx[4];
    #pragma unroll
    for (int r = 0; r < 4; ++r) {
      int qr = qt * 64 + w * 16 + g * 4 + r;
      float m0 = NEG;
      #pragma unroll
      for (int nf = 0; nf < 2; ++nf) {
        float x = sacc[nf][r] * isc;
        if (diag) { int col = kt * 32 + nf * 16 + li; if (col > qr) x = NEG; }
        p[nf][r] = x;
        m0 = fmaxf(m0, x);
      }
      m0 = fmaxf(m0, __shfl_xor(m0, 1));
      m0 = fmaxf(m0, __shfl_xor(m0, 2));
      m0 = fmaxf(m0, __shfl_xor(m0, 4));
      m0 = fmaxf(m0, __shfl_xor(m0, 8));
      mx[r] = m0;
    }
    bool need = (mx[0] > m_[0] + 8.f) || (mx[1] > m_[1] + 8.f) ||
                (mx[2] > m_[2] + 8.f) || (mx[3] > m_[3] + 8.f);
    if (__any(need)) {
      #pragma unroll
      for (int r = 0; r < 4; ++r) {
        float mn = fmaxf(m_[r], mx[r]);
        float sc = __expf(m_[r] - mn);
        l_[r] *= sc; m_[r] = mn;
        #pragma unroll
        for (int nf = 0; nf < 16; ++nf) o[nf][r] *= sc;
      }
    }
    #pragma unroll
    for (int r = 0; r < 4; ++r) {
      float rs = 0.f;
      #pragma unroll
      for (int nf = 0; nf < 2; ++nf) {
        float e = __expf(p[nf][r] - m_[r]);
        p[nf][r] = e;
        rs += e;
      }
      rs += __shfl_xor(rs, 1);
      rs += __shfl_xor(rs, 2);
      rs += __shfl_xor(rs, 4);
      rs += __shfl_xor(rs, 8);
      l_[r] += rs;
    }

    // V(kt) landed (K(kt+1)'s 4 loads stay in flight); all waves aligned
    if (more) asm volatile("s_waitcnt vmcnt(4)" ::: "memory");
    else      asm volatile("s_waitcnt vmcnt(0)" ::: "memory");
    asm volatile("s_barrier" ::: "memory");

    // P -> per-wave swizzled LDS (16x32, rows 64B, swz (row&3)<<4)
    #pragma unroll
    for (int r = 0; r < 4; ++r) {
      int row = g * 4 + r;
      int swz = (row & 3) << 4;
      #pragma unroll
      for (int nf = 0; nf < 2; ++nf)
        *(u16*)((char*)sP + w * 1024 + row * 64 + (((nf * 16 + li) * 2) ^ swz)) = f2bf(p[nf][r]);
    }
    asm volatile("s_waitcnt lgkmcnt(0)" ::: "memory");
    __builtin_amdgcn_sched_barrier(0);

    // O += P * V from LDS
    __builtin_amdgcn_s_setprio(1);
    {
      bf16x8 pa = ld8((const char*)sP + w * 1024 + li * 64 + ((g * 16) ^ ((li & 3) << 4)));
      #pragma unroll
      for (int nf = 0; nf < 16; ++nf) {
        int row = nf * 16 + li;
        bf16x8 vf = ld8((const char*)sV + row * 64 + ((g * 16) ^ ((row & 3) << 4)));
        o[nf] = __builtin_amdgcn_mfma_f32_16x16x32_bf16(pa, vf, o[nf], 0, 0, 0);
      }
    }
    __builtin_amdgcn_s_setprio(0);

    // all waves done reading sV -> next iter may overwrite it
    asm volatile("s_barrier" ::: "memory");
    // K(kt+1) landed before next QK
    if (more) asm volatile("s_waitcnt vmcnt(0)" ::: "memory");
    cur ^= 1;
  }

  // epilogue: 1/l, PMSNorm over d=256, *norm_weight, write merged bf16
  #pragma unroll
  for (int r = 0; r < 4; ++r) {
    float inv_l = 1.0f / l_[r];
    float ss = 0.f;
    #pragma unroll
    for (int nf = 0; nf < 16; ++nf) {
      float v = o[nf][r] * inv_l;
      ss += v * v;
    }
    ss += __shfl_xor(ss, 1);
    ss += __shfl_xor(ss, 2);
    ss += __shfl_xor(ss, 4);
    ss += __shfl_xor(ss, 8);
    float rms = rsqrtf(ss * (1.0f / 256.0f) + 1e-5f);
    int row = qt * 64 + w * 16 + g * 4 + r;
    #pragma unroll
    for (int nf = 0; nf < 16; ++nf) {
      int d = nf * 16 + li;
      float v = o[nf][r] * inv_l * rms * nw[d];
      Mrg[((size_t)(b * 2048 + row)) * 2048 + h * 256 + d] = f2bf(v);
    }
  }
}

extern "C" void kernel_launch(void* const* d_in, const int* in_sizes, int n_in,
                              void* d_out, int out_size, void* d_ws, size_t ws_size,
                              hipStream_t stream) {
  const float* hs  = (const float*)d_in[0];   // [2,2048,2048]
  const float* wat = (const float*)d_in[1];   // [2048,6144]
  const float* wpr = (const float*)d_in[2];   // [2048,2048]
  const float* nw  = (const float*)d_in[3];   // [256]
  float* out = (float*)d_out;                 // [2,2048,2048] f32

  char* ws = (char*)d_ws;
  u16* Xb   = (u16*)(ws + 0);                    // 16 MiB  [4096][2048] bf16
  u16* Wp_t = (u16*)(ws + (16u << 20));          //  8 MiB  [2048][2048] bf16 (w_proj^T)
  u16* Qkv  = (u16*)(ws + (24u << 20));          // 48 MiB  [4096][6144] bf16
  u16* Vt   = (u16*)(ws + (72u << 20));          // 16 MiB  [16][256][2048] bf16
  u16* Mrg  = Xb;                                // aliases Xb (dead after GEMM1)
  u16* Wa_t = (u16*)d_out;                       // 24 MiB scratch (w_attn^T [6144][2048])

  dim3 t328(32, 8);
  cast_bf16_kernel<<<4096, 256, 0, stream>>>(hs, Xb, 1048576);
  tcast_kernel<<<dim3(192, 64), t328, 0, stream>>>(wat, Wa_t, 2048, 6144);
  tcast_kernel<<<dim3(64, 64), t328, 0, stream>>>(wpr, Wp_t, 2048, 2048);
  gemm_bt_kernel<<<dim3(48, 32), 256, 0, stream>>>(Xb, Wa_t, nullptr, Qkv, 4096, 6144, 2048);
  tv_kernel<<<dim3(8, 64, 16), t328, 0, stream>>>(Qkv, Vt);
  attn_kernel<<<512, 256, 0, stream>>>(Qkv, Vt, nw, Mrg);
  gemm_bt_kernel<<<dim3(16, 32), 256, 0, stream>>>(Mrg, Wp_t, out, nullptr, 4096, 2048, 2048);
  (void)in_sizes; (void)n_in; (void)out_size; (void)ws_size;
}

// Round 4
// 321.277 us; speedup vs baseline: 1.2275x; 1.0798x over previous
//
#include <hip/hip_runtime.h>
#include <math.h>

// PGTAttention fused block, MI355X gfx950. Round 4.
// Change vs r3 (attn only): (1) lazy softmax — no cross-lane ops in the common path
// (lane-local max + __any trigger; lane-partial l reduced once in epilogue);
// (2) V/P LDS swizzles fixed from (row&3)<<4 (4-way conflict, period-4) to
// ((row>>1)&3)<<4 (2-way, period-8, free per m136); (3) QK MFMA split into 4
// accumulator chains (depth 8 -> 4). GEMMs unchanged.

typedef unsigned short u16;
typedef unsigned int   u32;
typedef u16   u16x8 __attribute__((ext_vector_type(8)));
typedef __bf16 bf16x8 __attribute__((ext_vector_type(8)));
typedef float f32x4 __attribute__((ext_vector_type(4)));

#define GPTR(p) ((const __attribute__((address_space(1))) void*)(p))
#define LPTR(p) ((__attribute__((address_space(3))) void*)(p))

__device__ __forceinline__ u16 f2bf(float x) {
  u32 u = __float_as_uint(x);
  return (u16)((u + 0x7fffu + ((u >> 16) & 1u)) >> 16);  // RNE
}

__device__ __forceinline__ bf16x8 ld8(const void* p) {
  u16x8 v = *reinterpret_cast<const u16x8*>(p);
  return __builtin_bit_cast(bf16x8, v);
}

// global->LDS direct copy, 16B/lane; LDS dest = wave-uniform base + lane*16.
__device__ __forceinline__ void g2l16(const void* g, void* l) {
  __builtin_amdgcn_global_load_lds(GPTR(g), LPTR(l), 16, 0, 0);
}

// ---------------- elementwise cast f32 -> bf16, 8 elems/thread ----------------
__global__ void cast_bf16_kernel(const float* __restrict__ in, u16* __restrict__ out, int n8) {
  int i = blockIdx.x * 256 + threadIdx.x;
  if (i >= n8) return;
  const float4* p = reinterpret_cast<const float4*>(in) + (size_t)i * 2;
  float4 a = p[0], b = p[1];
  u16x8 v;
  v[0] = f2bf(a.x); v[1] = f2bf(a.y); v[2] = f2bf(a.z); v[3] = f2bf(a.w);
  v[4] = f2bf(b.x); v[5] = f2bf(b.y); v[6] = f2bf(b.z); v[7] = f2bf(b.w);
  reinterpret_cast<u16x8*>(out)[i] = v;
}

// ---------------- transpose + cast: out[c][r] = bf16(in[r][c]), in is R x C f32 -------
__global__ void tcast_kernel(const float* __restrict__ in, u16* __restrict__ out, int R, int C) {
  __shared__ float t[32][33];
  int bx = blockIdx.x * 32, by = blockIdx.y * 32;
  int x = threadIdx.x, y = threadIdx.y;  // (32, 8)
  #pragma unroll
  for (int k = 0; k < 32; k += 8)
    t[y + k][x] = in[(size_t)(by + y + k) * C + (bx + x)];
  __syncthreads();
  #pragma unroll
  for (int k = 0; k < 32; k += 8)
    out[(size_t)(bx + y + k) * R + (by + x)] = f2bf(t[x][y + k]);
}

// ------- V transpose from qkv: out[bh][d][s] = qkv[b][s][4096 + h*256 + d] ----------
__global__ void tv_kernel(const u16* __restrict__ qkv, u16* __restrict__ out) {
  __shared__ u16 t[32][33];
  int bh = blockIdx.z, b = bh >> 3, h = bh & 7;
  const u16* ip = qkv + (size_t)b * 2048 * 6144 + 4096 + h * 256;
  u16* op = out + (size_t)bh * 256 * 2048;
  int bx = blockIdx.x * 32, by = blockIdx.y * 32;  // bx: d, by: s
  int x = threadIdx.x, y = threadIdx.y;
  #pragma unroll
  for (int k = 0; k < 32; k += 8)
    t[y + k][x] = ip[(size_t)(by + y + k) * 6144 + (bx + x)];
  __syncthreads();
  #pragma unroll
  for (int k = 0; k < 32; k += 8)
    op[(size_t)(bx + y + k) * 2048 + (by + x)] = t[x][y + k];
}

// ---------------- GEMM: C[M,N] = A[M,K] * Bt[N,K]^T  (bf16 in, f32 acc) ----------------
// 128x128 tile, BK=64 (single 32KB buffer), 4 waves each 64x64. Unchanged from r2/r3.
__global__ __launch_bounds__(256) void gemm_bt_kernel(
    const u16* __restrict__ A, const u16* __restrict__ Bt,
    float* __restrict__ Cf, u16* __restrict__ Cb, int M, int N, int K) {
  __shared__ __align__(16) u16 sA[128 * 64];  // 16 KiB
  __shared__ __align__(16) u16 sB[128 * 64];  // 16 KiB
  const int tid = threadIdx.x;
  const int lane = tid & 63, w = tid >> 6;
  const int wr = w >> 1, wc = w & 1;
  const int g = lane >> 4, li = lane & 15;
  const int bn = blockIdx.x * 128, bm = blockIdx.y * 128;

  const char* aSrc[4]; const char* bSrc[4];
  char* aDst[4]; char* bDst[4];
  #pragma unroll
  for (int j = 0; j < 4; ++j) {
    int chunk = w * 4 + j;
    int o = chunk * 1024 + lane * 16;
    int row = o >> 7, cb = o & 127;
    int cbs = cb ^ ((row & 7) << 4);
    aSrc[j] = (const char*)A + (size_t)(bm + row) * K * 2 + cbs;
    bSrc[j] = (const char*)Bt + (size_t)(bn + row) * K * 2 + cbs;
    aDst[j] = (char*)sA + chunk * 1024;
    bDst[j] = (char*)sB + chunk * 1024;
  }
  const char* aRd[2][4]; const char* bRd[2][4];
  #pragma unroll
  for (int ks = 0; ks < 2; ++ks) {
    #pragma unroll
    for (int f = 0; f < 4; ++f) {
      int ra = wr * 64 + f * 16 + li;
      aRd[ks][f] = (const char*)sA + ra * 128 + ((ks * 64 + g * 16) ^ ((ra & 7) << 4));
      int rb = wc * 64 + f * 16 + li;
      bRd[ks][f] = (const char*)sB + rb * 128 + ((ks * 64 + g * 16) ^ ((rb & 7) << 4));
    }
  }

  const f32x4 fz = {0.f, 0.f, 0.f, 0.f};
  f32x4 acc[4][4];
  #pragma unroll
  for (int i = 0; i < 4; ++i)
    #pragma unroll
    for (int j = 0; j < 4; ++j) acc[i][j] = fz;

  for (int k0 = 0; k0 < K; k0 += 64) {
    #pragma unroll
    for (int j = 0; j < 4; ++j) { g2l16(aSrc[j], aDst[j]); g2l16(bSrc[j], bDst[j]); }
    #pragma unroll
    for (int j = 0; j < 4; ++j) { aSrc[j] += 128; bSrc[j] += 128; }
    __syncthreads();
    bf16x8 af[2][4], bfv[2][4];
    #pragma unroll
    for (int ks = 0; ks < 2; ++ks)
      #pragma unroll
      for (int f = 0; f < 4; ++f) { af[ks][f] = ld8(aRd[ks][f]); bfv[ks][f] = ld8(bRd[ks][f]); }
    #pragma unroll
    for (int ks = 0; ks < 2; ++ks)
      #pragma unroll
      for (int mf = 0; mf < 4; ++mf)
        #pragma unroll
        for (int nf = 0; nf < 4; ++nf)
          acc[mf][nf] = __builtin_amdgcn_mfma_f32_16x16x32_bf16(af[ks][mf], bfv[ks][nf], acc[mf][nf], 0, 0, 0);
    __syncthreads();
  }

  if (Cf) {
    #pragma unroll
    for (int mf = 0; mf < 4; ++mf)
      #pragma unroll
      for (int nf = 0; nf < 4; ++nf)
        #pragma unroll
        for (int r = 0; r < 4; ++r) {
          int gm = bm + wr * 64 + mf * 16 + g * 4 + r;
          int gn = bn + wc * 64 + nf * 16 + li;
          Cf[(size_t)gm * N + gn] = acc[mf][nf][r];
        }
  } else {
    #pragma unroll
    for (int mf = 0; mf < 4; ++mf)
      #pragma unroll
      for (int nf = 0; nf < 4; ++nf)
        #pragma unroll
        for (int r = 0; r < 4; ++r) {
          int gm = bm + wr * 64 + mf * 16 + g * 4 + r;
          int gn = bn + wc * 64 + nf * 16 + li;
          Cb[(size_t)gm * N + gn] = f2bf(acc[mf][nf][r]);
        }
  }
}

// ---------------- flash attention + fused PMSNorm ----------------
// 256 thr (4 waves), q-tile 64 (16 rows/wave), KVBLK=32.
// sK dbuf (2x16KB, swz (row&7)<<4), sV single (16KB [256 d][32 s], swz ((row>>1)&3)<<4),
// sP per-wave 16x32 (same swz). Counted-vmcnt pipeline as r3. Lazy softmax:
// common path has NO shuffles; l is lane-partial (reduced in epilogue); group max
// refresh only on __any(lane-max > m+8).
__global__ __launch_bounds__(256) void attn_kernel(
    const u16* __restrict__ qkv, const u16* __restrict__ Vt,
    const float* __restrict__ nw, u16* __restrict__ Mrg) {
  __shared__ __align__(16) u16 sK[2][32 * 256];   // 32 KiB
  __shared__ __align__(16) u16 sV[256 * 32];      // 16 KiB
  __shared__ __align__(16) u16 sP[4 * 16 * 32];   //  4 KiB

  // causal load balance: pair q-tiles i and 31-i
  int flat = blockIdx.x;
  int u = flat & 255, pp = flat >> 8;
  int bh = u & 15, i0 = u >> 4;
  int qt = pp ? 31 - i0 : i0;
  int b = bh >> 3, h = bh & 7;

  const int tid = threadIdx.x, lane = tid & 63, w = tid >> 6;
  const int g = lane >> 4, li = lane & 15;
  const float NEG = -__builtin_inff();

  // hoist Q fragments (16 rows/wave)
  int qrow = qt * 64 + w * 16 + li;
  const u16* qp = qkv + (size_t)(b * 2048 + qrow) * 6144 + h * 256;
  bf16x8 qf[8];
  #pragma unroll
  for (int c = 0; c < 8; ++c) qf[c] = ld8(qp + c * 32 + g * 8);

  // K staging: tile [32][256] = 16KB = 16 chunks, 4/wave; rows 512B, swz (row&7)<<4
  const size_t KADV = (size_t)32 * 6144 * 2;
  const char* kSrc[4]; u32 kDoff[4];
  #pragma unroll
  for (int j = 0; j < 4; ++j) {
    int chunk = w * 4 + j;
    int o = chunk * 1024 + lane * 16;
    int row = o >> 9, cb = o & 511;
    int cbs = cb ^ ((row & 7) << 4);
    kSrc[j] = (const char*)qkv + ((size_t)(b * 2048 + row) * 6144 + 2048 + h * 256) * 2 + cbs;
    kDoff[j] = chunk * 1024;
  }
  // V staging: tile [256 d][32 s] = 16KB, rows 64B, swz ((row>>1)&3)<<4
  const char* vSrc[4]; char* vDst[4];
  #pragma unroll
  for (int j = 0; j < 4; ++j) {
    int chunk = w * 4 + j;
    int o = chunk * 1024 + lane * 16;
    int row = o >> 6, cb = o & 63;
    int cbs = cb ^ (((row >> 1) & 3) << 4);
    vSrc[j] = (const char*)Vt + ((size_t)(bh * 256 + row) * 2048) * 2 + cbs;
    vDst[j] = (char*)sV + chunk * 1024;
  }

  const f32x4 fz = {0.f, 0.f, 0.f, 0.f};
  f32x4 o[16];
  #pragma unroll
  for (int nf = 0; nf < 16; ++nf) o[nf] = fz;
  float m_[4] = {NEG, NEG, NEG, NEG};
  float l_[4] = {0.f, 0.f, 0.f, 0.f};   // lane-partial (cols owned by this lane)

  // prologue: stage K(0) into sK[0]
  #pragma unroll
  for (int j = 0; j < 4; ++j) { g2l16(kSrc[j], (char*)sK[0] + kDoff[j]); kSrc[j] += KADV; }
  asm volatile("s_waitcnt vmcnt(0)" ::: "memory");
  __syncthreads();

  int cur = 0;
  const int ktn = 2 * qt + 1;  // k-tiles of 32, cols up to 64*qt+63
  for (int kt = 0; kt <= ktn; ++kt) {
    const bool more = (kt < ktn);
    // issue V(kt) (sV free: post-PV barrier of prev iter) and K(kt+1) (alt buffer)
    #pragma unroll
    for (int j = 0; j < 4; ++j) { g2l16(vSrc[j], vDst[j]); vSrc[j] += 64; }
    if (more) {
      char* kb = (char*)sK[cur ^ 1];
      #pragma unroll
      for (int j = 0; j < 4; ++j) { g2l16(kSrc[j], kb + kDoff[j]); kSrc[j] += KADV; }
    }

    // S = Q * K^T from sK[cur]; 4 accumulator chains (depth 4)
    f32x4 sacc[2];
    const char* kbase = (const char*)sK[cur];
    __builtin_amdgcn_s_setprio(1);
    #pragma unroll
    for (int nf = 0; nf < 2; ++nf) {
      int row = nf * 16 + li;
      int swz = (row & 7) << 4;
      const char* kr = kbase + row * 512;
      f32x4 sa = fz, sb = fz;
      #pragma unroll
      for (int c = 0; c < 4; ++c) {
        sa = __builtin_amdgcn_mfma_f32_16x16x32_bf16(qf[c],     ld8(kr + ((c * 64 + g * 16) ^ swz)),       sa, 0, 0, 0);
        sb = __builtin_amdgcn_mfma_f32_16x16x32_bf16(qf[c + 4], ld8(kr + (((c + 4) * 64 + g * 16) ^ swz)), sb, 0, 0, 0);
      }
      sacc[nf] = sa + sb;
    }
    __builtin_amdgcn_s_setprio(0);

    // lazy softmax: lane-local max + __any trigger; no shuffles in common path
    const float isc = 1.0f / 64.0f;  // sqrt(256) * (LAYER_IDX+1)
    const bool diag = (kt >= 2 * qt);
    float p[2][4], m0[4];
    #pragma unroll
    for (int r = 0; r < 4; ++r) {
      int qr = qt * 64 + w * 16 + g * 4 + r;
      float a0 = sacc[0][r] * isc;
      float a1 = sacc[1][r] * isc;
      if (diag) {
        if (kt * 32 + li > qr) a0 = NEG;
        if (kt * 32 + 16 + li > qr) a1 = NEG;
      }
      p[0][r] = a0; p[1][r] = a1;
      m0[r] = fmaxf(a0, a1);
    }
    bool need = (m0[0] > m_[0] + 8.f) || (m0[1] > m_[1] + 8.f) ||
                (m0[2] > m_[2] + 8.f) || (m0[3] > m_[3] + 8.f);
    if (__any(need)) {  // wave-uniform branch; shuffles safe inside
      #pragma unroll
      for (int r = 0; r < 4; ++r) {
        float mx = m0[r];
        mx = fmaxf(mx, __shfl_xor(mx, 1));
        mx = fmaxf(mx, __shfl_xor(mx, 2));
        mx = fmaxf(mx, __shfl_xor(mx, 4));
        mx = fmaxf(mx, __shfl_xor(mx, 8));
        float mn = fmaxf(m_[r], mx);
        float sc = __expf(m_[r] - mn);
        l_[r] *= sc; m_[r] = mn;
        #pragma unroll
        for (int nf = 0; nf < 16; ++nf) o[nf][r] *= sc;
      }
    }
    #pragma unroll
    for (int r = 0; r < 4; ++r) {
      float e0 = __expf(p[0][r] - m_[r]);
      float e1 = __expf(p[1][r] - m_[r]);
      p[0][r] = e0; p[1][r] = e1;
      l_[r] += e0 + e1;  // lane-partial; reduced once in epilogue
    }

    // V(kt) landed (K(kt+1)'s 4 loads stay in flight); all waves aligned
    if (more) asm volatile("s_waitcnt vmcnt(4)" ::: "memory");
    else      asm volatile("s_waitcnt vmcnt(0)" ::: "memory");
    asm volatile("s_barrier" ::: "memory");

    // P -> per-wave swizzled LDS (16x32, rows 64B, swz ((row>>1)&3)<<4)
    #pragma unroll
    for (int r = 0; r < 4; ++r) {
      int row = g * 4 + r;
      int swz = ((row >> 1) & 3) << 4;
      #pragma unroll
      for (int nf = 0; nf < 2; ++nf)
        *(u16*)((char*)sP + w * 1024 + row * 64 + (((nf * 16 + li) * 2) ^ swz)) = f2bf(p[nf][r]);
    }
    asm volatile("s_waitcnt lgkmcnt(0)" ::: "memory");
    __builtin_amdgcn_sched_barrier(0);

    // O += P * V from LDS
    __builtin_amdgcn_s_setprio(1);
    {
      bf16x8 pa = ld8((const char*)sP + w * 1024 + li * 64 + ((g * 16) ^ (((li >> 1) & 3) << 4)));
      #pragma unroll
      for (int nf = 0; nf < 16; ++nf) {
        int row = nf * 16 + li;
        bf16x8 vf = ld8((const char*)sV + row * 64 + ((g * 16) ^ (((row >> 1) & 3) << 4)));
        o[nf] = __builtin_amdgcn_mfma_f32_16x16x32_bf16(pa, vf, o[nf], 0, 0, 0);
      }
    }
    __builtin_amdgcn_s_setprio(0);

    // all waves done reading sV -> next iter may overwrite it
    asm volatile("s_barrier" ::: "memory");
    // K(kt+1) landed before next QK
    if (more) asm volatile("s_waitcnt vmcnt(0)" ::: "memory");
    cur ^= 1;
  }

  // epilogue: reduce lane-partial l, then 1/l, PMSNorm over d=256, *nw, write bf16
  #pragma unroll
  for (int r = 0; r < 4; ++r) {
    float ls = l_[r];
    ls += __shfl_xor(ls, 1);
    ls += __shfl_xor(ls, 2);
    ls += __shfl_xor(ls, 4);
    ls += __shfl_xor(ls, 8);
    float inv_l = 1.0f / ls;
    float ss = 0.f;
    #pragma unroll
    for (int nf = 0; nf < 16; ++nf) {
      float v = o[nf][r] * inv_l;
      ss += v * v;
    }
    ss += __shfl_xor(ss, 1);
    ss += __shfl_xor(ss, 2);
    ss += __shfl_xor(ss, 4);
    ss += __shfl_xor(ss, 8);
    float rms = rsqrtf(ss * (1.0f / 256.0f) + 1e-5f);
    int row = qt * 64 + w * 16 + g * 4 + r;
    #pragma unroll
    for (int nf = 0; nf < 16; ++nf) {
      int d = nf * 16 + li;
      float v = o[nf][r] * inv_l * rms * nw[d];
      Mrg[((size_t)(b * 2048 + row)) * 2048 + h * 256 + d] = f2bf(v);
    }
  }
}

extern "C" void kernel_launch(void* const* d_in, const int* in_sizes, int n_in,
                              void* d_out, int out_size, void* d_ws, size_t ws_size,
                              hipStream_t stream) {
  const float* hs  = (const float*)d_in[0];   // [2,2048,2048]
  const float* wat = (const float*)d_in[1];   // [2048,6144]
  const float* wpr = (const float*)d_in[2];   // [2048,2048]
  const float* nw  = (const float*)d_in[3];   // [256]
  float* out = (float*)d_out;                 // [2,2048,2048] f32

  char* ws = (char*)d_ws;
  u16* Xb   = (u16*)(ws + 0);                    // 16 MiB  [4096][2048] bf16
  u16* Wp_t = (u16*)(ws + (16u << 20));          //  8 MiB  [2048][2048] bf16 (w_proj^T)
  u16* Qkv  = (u16*)(ws + (24u << 20));          // 48 MiB  [4096][6144] bf16
  u16* Vt   = (u16*)(ws + (72u << 20));          // 16 MiB  [16][256][2048] bf16
  u16* Mrg  = Xb;                                // aliases Xb (dead after GEMM1)
  u16* Wa_t = (u16*)d_out;                       // 24 MiB scratch (w_attn^T [6144][2048])

  dim3 t328(32, 8);
  cast_bf16_kernel<<<4096, 256, 0, stream>>>(hs, Xb, 1048576);
  tcast_kernel<<<dim3(192, 64), t328, 0, stream>>>(wat, Wa_t, 2048, 6144);
  tcast_kernel<<<dim3(64, 64), t328, 0, stream>>>(wpr, Wp_t, 2048, 2048);
  gemm_bt_kernel<<<dim3(48, 32), 256, 0, stream>>>(Xb, Wa_t, nullptr, Qkv, 4096, 6144, 2048);
  tv_kernel<<<dim3(8, 64, 16), t328, 0, stream>>>(Qkv, Vt);
  attn_kernel<<<512, 256, 0, stream>>>(Qkv, Vt, nw, Mrg);
  gemm_bt_kernel<<<dim3(16, 32), 256, 0, stream>>>(Mrg, Wp_t, out, nullptr, 4096, 2048, 2048);
  (void)in_sizes; (void)n_in; (void)out_size; (void)ws_size;
}

// Round 5
// 268.869 us; speedup vs baseline: 1.4668x; 1.1949x over previous
//
#include <hip/hip_runtime.h>
#include <math.h>

// PGTAttention fused block, MI355X gfx950. Round 5.
// Change vs r4 (attn only): makespan fix. 256 blocks x 8 waves; each block owns
// q-tiles {i, 31-i} sequentially (uniform 66 KV-tiles/block, zero tail); the 8
// waves split into two independent 4-wave halves processing disjoint contiguous
// KV halves (split-k). Lazy softmax needs no per-tile cross-half sync; one LDS
// merge per unit (flash-decoding combine). Finite mask constants (-30000/-1000)
// replace -inf (NaN hazard on fully-masked rows). GEMMs/preps unchanged.

typedef unsigned short u16;
typedef unsigned int   u32;
typedef u16   u16x8 __attribute__((ext_vector_type(8)));
typedef __bf16 bf16x8 __attribute__((ext_vector_type(8)));
typedef float f32x4 __attribute__((ext_vector_type(4)));

#define GPTR(p) ((const __attribute__((address_space(1))) void*)(p))
#define LPTR(p) ((__attribute__((address_space(3))) void*)(p))

__device__ __forceinline__ u16 f2bf(float x) {
  u32 u = __float_as_uint(x);
  return (u16)((u + 0x7fffu + ((u >> 16) & 1u)) >> 16);  // RNE
}

__device__ __forceinline__ bf16x8 ld8(const void* p) {
  u16x8 v = *reinterpret_cast<const u16x8*>(p);
  return __builtin_bit_cast(bf16x8, v);
}

// global->LDS direct copy, 16B/lane; LDS dest = wave-uniform base + lane*16.
__device__ __forceinline__ void g2l16(const void* g, void* l) {
  __builtin_amdgcn_global_load_lds(GPTR(g), LPTR(l), 16, 0, 0);
}

// ---------------- elementwise cast f32 -> bf16, 8 elems/thread ----------------
__global__ void cast_bf16_kernel(const float* __restrict__ in, u16* __restrict__ out, int n8) {
  int i = blockIdx.x * 256 + threadIdx.x;
  if (i >= n8) return;
  const float4* p = reinterpret_cast<const float4*>(in) + (size_t)i * 2;
  float4 a = p[0], b = p[1];
  u16x8 v;
  v[0] = f2bf(a.x); v[1] = f2bf(a.y); v[2] = f2bf(a.z); v[3] = f2bf(a.w);
  v[4] = f2bf(b.x); v[5] = f2bf(b.y); v[6] = f2bf(b.z); v[7] = f2bf(b.w);
  reinterpret_cast<u16x8*>(out)[i] = v;
}

// ---------------- transpose + cast: out[c][r] = bf16(in[r][c]), in is R x C f32 -------
__global__ void tcast_kernel(const float* __restrict__ in, u16* __restrict__ out, int R, int C) {
  __shared__ float t[32][33];
  int bx = blockIdx.x * 32, by = blockIdx.y * 32;
  int x = threadIdx.x, y = threadIdx.y;  // (32, 8)
  #pragma unroll
  for (int k = 0; k < 32; k += 8)
    t[y + k][x] = in[(size_t)(by + y + k) * C + (bx + x)];
  __syncthreads();
  #pragma unroll
  for (int k = 0; k < 32; k += 8)
    out[(size_t)(bx + y + k) * R + (by + x)] = f2bf(t[x][y + k]);
}

// ------- V transpose from qkv: out[bh][d][s] = qkv[b][s][4096 + h*256 + d] ----------
__global__ void tv_kernel(const u16* __restrict__ qkv, u16* __restrict__ out) {
  __shared__ u16 t[32][33];
  int bh = blockIdx.z, b = bh >> 3, h = bh & 7;
  const u16* ip = qkv + (size_t)b * 2048 * 6144 + 4096 + h * 256;
  u16* op = out + (size_t)bh * 256 * 2048;
  int bx = blockIdx.x * 32, by = blockIdx.y * 32;  // bx: d, by: s
  int x = threadIdx.x, y = threadIdx.y;
  #pragma unroll
  for (int k = 0; k < 32; k += 8)
    t[y + k][x] = ip[(size_t)(by + y + k) * 6144 + (bx + x)];
  __syncthreads();
  #pragma unroll
  for (int k = 0; k < 32; k += 8)
    op[(size_t)(bx + y + k) * 2048 + (by + x)] = t[x][y + k];
}

// ---------------- GEMM: C[M,N] = A[M,K] * Bt[N,K]^T  (bf16 in, f32 acc) ----------------
// 128x128 tile, BK=64 (single 32KB buffer), 4 waves each 64x64. Unchanged from r2-r4.
__global__ __launch_bounds__(256) void gemm_bt_kernel(
    const u16* __restrict__ A, const u16* __restrict__ Bt,
    float* __restrict__ Cf, u16* __restrict__ Cb, int M, int N, int K) {
  __shared__ __align__(16) u16 sA[128 * 64];  // 16 KiB
  __shared__ __align__(16) u16 sB[128 * 64];  // 16 KiB
  const int tid = threadIdx.x;
  const int lane = tid & 63, w = tid >> 6;
  const int wr = w >> 1, wc = w & 1;
  const int g = lane >> 4, li = lane & 15;
  const int bn = blockIdx.x * 128, bm = blockIdx.y * 128;

  const char* aSrc[4]; const char* bSrc[4];
  char* aDst[4]; char* bDst[4];
  #pragma unroll
  for (int j = 0; j < 4; ++j) {
    int chunk = w * 4 + j;
    int o = chunk * 1024 + lane * 16;
    int row = o >> 7, cb = o & 127;
    int cbs = cb ^ ((row & 7) << 4);
    aSrc[j] = (const char*)A + (size_t)(bm + row) * K * 2 + cbs;
    bSrc[j] = (const char*)Bt + (size_t)(bn + row) * K * 2 + cbs;
    aDst[j] = (char*)sA + chunk * 1024;
    bDst[j] = (char*)sB + chunk * 1024;
  }
  const char* aRd[2][4]; const char* bRd[2][4];
  #pragma unroll
  for (int ks = 0; ks < 2; ++ks) {
    #pragma unroll
    for (int f = 0; f < 4; ++f) {
      int ra = wr * 64 + f * 16 + li;
      aRd[ks][f] = (const char*)sA + ra * 128 + ((ks * 64 + g * 16) ^ ((ra & 7) << 4));
      int rb = wc * 64 + f * 16 + li;
      bRd[ks][f] = (const char*)sB + rb * 128 + ((ks * 64 + g * 16) ^ ((rb & 7) << 4));
    }
  }

  const f32x4 fz = {0.f, 0.f, 0.f, 0.f};
  f32x4 acc[4][4];
  #pragma unroll
  for (int i = 0; i < 4; ++i)
    #pragma unroll
    for (int j = 0; j < 4; ++j) acc[i][j] = fz;

  for (int k0 = 0; k0 < K; k0 += 64) {
    #pragma unroll
    for (int j = 0; j < 4; ++j) { g2l16(aSrc[j], aDst[j]); g2l16(bSrc[j], bDst[j]); }
    #pragma unroll
    for (int j = 0; j < 4; ++j) { aSrc[j] += 128; bSrc[j] += 128; }
    __syncthreads();
    bf16x8 af[2][4], bfv[2][4];
    #pragma unroll
    for (int ks = 0; ks < 2; ++ks)
      #pragma unroll
      for (int f = 0; f < 4; ++f) { af[ks][f] = ld8(aRd[ks][f]); bfv[ks][f] = ld8(bRd[ks][f]); }
    #pragma unroll
    for (int ks = 0; ks < 2; ++ks)
      #pragma unroll
      for (int mf = 0; mf < 4; ++mf)
        #pragma unroll
        for (int nf = 0; nf < 4; ++nf)
          acc[mf][nf] = __builtin_amdgcn_mfma_f32_16x16x32_bf16(af[ks][mf], bfv[ks][nf], acc[mf][nf], 0, 0, 0);
    __syncthreads();
  }

  if (Cf) {
    #pragma unroll
    for (int mf = 0; mf < 4; ++mf)
      #pragma unroll
      for (int nf = 0; nf < 4; ++nf)
        #pragma unroll
        for (int r = 0; r < 4; ++r) {
          int gm = bm + wr * 64 + mf * 16 + g * 4 + r;
          int gn = bn + wc * 64 + nf * 16 + li;
          Cf[(size_t)gm * N + gn] = acc[mf][nf][r];
        }
  } else {
    #pragma unroll
    for (int mf = 0; mf < 4; ++mf)
      #pragma unroll
      for (int nf = 0; nf < 4; ++nf)
        #pragma unroll
        for (int r = 0; r < 4; ++r) {
          int gm = bm + wr * 64 + mf * 16 + g * 4 + r;
          int gn = bn + wc * 64 + nf * 16 + li;
          Cb[(size_t)gm * N + gn] = f2bf(acc[mf][nf][r]);
        }
  }
}

// ---------------- flash attention + fused PMSNorm (split-k, balanced) ----------------
// 256 blocks x 512 thr. Block c: bh=c&15, i=c>>4; units qt={i, 31-i} sequential.
// Waves: kh=w>>2 (KV half), wq=w&3 (16 q-rows). Per half: own K dbuf + V + P pipeline
// (identical structure to r4); halves run equal tile counts -> block barriers align.
// Per-unit LDS merge combines the two halves (flash-decoding rescale), then PMSNorm.
__global__ __launch_bounds__(512, 2) void attn_kernel(
    const u16* __restrict__ qkv, const u16* __restrict__ Vt,
    const float* __restrict__ nw, u16* __restrict__ Mrg) {
  __shared__ __align__(16) char smem[106496];       // 104 KiB
  // layout: sK 64KB [kh][buf] 16KB each | sV 32KB [kh] 16KB | sP 8KB [kh][wq] 1KB
  char* sKb = smem;
  char* sVb = smem + 65536;
  char* sPb = smem + 65536 + 32768;
  float* oex  = (float*)smem;            // unit-merge exchange: [wq]*4096 + nf*256 + lane*4
  float* mlex = (float*)(smem + 65536);  // [wq]*512 + {l:0, m:256} + r*64 + lane

  const int c = blockIdx.x;
  const int bh = c & 15, iu = c >> 4;
  const int b = bh >> 3, h = bh & 7;
  const int tid = threadIdx.x, lane = tid & 63, w = tid >> 6;
  const int kh = w >> 2, wq = w & 3;
  const int g = lane >> 4, li = lane & 15;
  const float MASKV = -30000.0f;  // exp(MASKV - m) flushes to 0 for any real m
  const float MINIT = -1000.0f;   // below any real score; exp(MASKV-MINIT)=0 too
  const float isc = 1.0f / 64.0f; // 1 / (sqrt(256) * (LAYER_IDX+1))
  const f32x4 fz = {0.f, 0.f, 0.f, 0.f};
  const size_t KADV = (size_t)32 * 6144 * 2;

  #pragma unroll 1
  for (int uu = 0; uu < 2; ++uu) {
    const int qt = uu ? (31 - iu) : iu;
    const int nt = qt + 1;          // tiles per half (32 KV rows each)
    const int kvb0 = kh * nt * 32;  // this half's KV start row

    // Q fragments (16 rows/wave)
    int qrow = qt * 64 + wq * 16 + li;
    const u16* qp = qkv + (size_t)(b * 2048 + qrow) * 6144 + h * 256;
    bf16x8 qf[8];
    #pragma unroll
    for (int c8 = 0; c8 < 8; ++c8) qf[c8] = ld8(qp + c8 * 32 + g * 8);

    // K staging: [32][256] 16KB/half = 16 chunks, 4/wave; rows 512B, swz (row&7)<<4
    const char* kSrc[4]; u32 kDoff[4];
    #pragma unroll
    for (int j = 0; j < 4; ++j) {
      int chunk = wq * 4 + j;
      int o = chunk * 1024 + lane * 16;
      int row = o >> 9, cb = o & 511;
      int cbs = cb ^ ((row & 7) << 4);
      kSrc[j] = (const char*)qkv + ((size_t)(b * 2048 + kvb0 + row) * 6144 + 2048 + h * 256) * 2 + cbs;
      kDoff[j] = chunk * 1024;
    }
    // V staging: [256 d][32 s] 16KB/half, rows 64B, swz ((row>>1)&3)<<4
    const char* vSrc[4]; char* vDst[4];
    #pragma unroll
    for (int j = 0; j < 4; ++j) {
      int chunk = wq * 4 + j;
      int o = chunk * 1024 + lane * 16;
      int row = o >> 6, cb = o & 63;
      int cbs = cb ^ (((row >> 1) & 3) << 4);
      vSrc[j] = (const char*)Vt + ((size_t)(bh * 256 + row) * 2048 + kvb0) * 2 + cbs;
      vDst[j] = sVb + kh * 16384 + chunk * 1024;
    }

    f32x4 o_[16];
    #pragma unroll
    for (int nf = 0; nf < 16; ++nf) o_[nf] = fz;
    float m_[4] = {MINIT, MINIT, MINIT, MINIT};
    float l_[4] = {0.f, 0.f, 0.f, 0.f};  // lane-partial

    // prologue: stage K(0) into own half's buf 0
    {
      char* kb0 = sKb + (kh * 2 + 0) * 16384;
      #pragma unroll
      for (int j = 0; j < 4; ++j) { g2l16(kSrc[j], kb0 + kDoff[j]); kSrc[j] += KADV; }
    }
    asm volatile("s_waitcnt vmcnt(0)" ::: "memory");
    asm volatile("s_barrier" ::: "memory");

    int cur = 0;
    for (int t = 0; t < nt; ++t) {
      const bool more = (t < nt - 1);
      // issue V(t) + K(t+1)
      #pragma unroll
      for (int j = 0; j < 4; ++j) { g2l16(vSrc[j], vDst[j]); vSrc[j] += 64; }
      if (more) {
        char* kb = sKb + (kh * 2 + (cur ^ 1)) * 16384;
        #pragma unroll
        for (int j = 0; j < 4; ++j) { g2l16(kSrc[j], kb + kDoff[j]); kSrc[j] += KADV; }
      }

      // S = Q * K^T ; 4 accumulator chains (depth 4)
      f32x4 sacc[2];
      const char* kbase = sKb + (kh * 2 + cur) * 16384;
      __builtin_amdgcn_s_setprio(1);
      #pragma unroll
      for (int nf = 0; nf < 2; ++nf) {
        int row = nf * 16 + li;
        int swz = (row & 7) << 4;
        const char* kr = kbase + row * 512;
        f32x4 sa = fz, sb = fz;
        #pragma unroll
        for (int c8 = 0; c8 < 4; ++c8) {
          sa = __builtin_amdgcn_mfma_f32_16x16x32_bf16(qf[c8],     ld8(kr + ((c8 * 64 + g * 16) ^ swz)),       sa, 0, 0, 0);
          sb = __builtin_amdgcn_mfma_f32_16x16x32_bf16(qf[c8 + 4], ld8(kr + (((c8 + 4) * 64 + g * 16) ^ swz)), sb, 0, 0, 0);
        }
        sacc[nf] = sa + sb;
      }
      __builtin_amdgcn_s_setprio(0);

      // lazy softmax; global tile index for masking
      const int tidx = kh * nt + t;
      const bool diag = (tidx >= 2 * qt);
      float p[2][4], m0[4];
      #pragma unroll
      for (int r = 0; r < 4; ++r) {
        int qr = qt * 64 + wq * 16 + g * 4 + r;
        float a0 = sacc[0][r] * isc;
        float a1 = sacc[1][r] * isc;
        if (diag) {
          if (tidx * 32 + li > qr) a0 = MASKV;
          if (tidx * 32 + 16 + li > qr) a1 = MASKV;
        }
        p[0][r] = a0; p[1][r] = a1;
        m0[r] = fmaxf(a0, a1);
      }
      bool need = (m0[0] > m_[0] + 8.f) || (m0[1] > m_[1] + 8.f) ||
                  (m0[2] > m_[2] + 8.f) || (m0[3] > m_[3] + 8.f);
      if (__any(need)) {  // wave-uniform branch
        #pragma unroll
        for (int r = 0; r < 4; ++r) {
          float mx = m0[r];
          mx = fmaxf(mx, __shfl_xor(mx, 1));
          mx = fmaxf(mx, __shfl_xor(mx, 2));
          mx = fmaxf(mx, __shfl_xor(mx, 4));
          mx = fmaxf(mx, __shfl_xor(mx, 8));
          float mn = fmaxf(m_[r], mx);
          float sc = __expf(m_[r] - mn);
          l_[r] *= sc; m_[r] = mn;
          #pragma unroll
          for (int nf = 0; nf < 16; ++nf) o_[nf][r] *= sc;
        }
      }
      #pragma unroll
      for (int r = 0; r < 4; ++r) {
        float e0 = __expf(p[0][r] - m_[r]);
        float e1 = __expf(p[1][r] - m_[r]);
        p[0][r] = e0; p[1][r] = e1;
        l_[r] += e0 + e1;
      }

      // own V landed (K(t+1) stays in flight); align all waves
      if (more) asm volatile("s_waitcnt vmcnt(4)" ::: "memory");
      else      asm volatile("s_waitcnt vmcnt(0)" ::: "memory");
      asm volatile("s_barrier" ::: "memory");

      // P -> per-wave swizzled LDS (16x32, rows 64B, swz ((row>>1)&3)<<4)
      char* sPw = sPb + kh * 4096 + wq * 1024;
      #pragma unroll
      for (int r = 0; r < 4; ++r) {
        int row = g * 4 + r;
        int swz = ((row >> 1) & 3) << 4;
        #pragma unroll
        for (int nf = 0; nf < 2; ++nf)
          *(u16*)(sPw + row * 64 + (((nf * 16 + li) * 2) ^ swz)) = f2bf(p[nf][r]);
      }
      asm volatile("s_waitcnt lgkmcnt(0)" ::: "memory");
      __builtin_amdgcn_sched_barrier(0);

      // O += P * V from own half's sV
      __builtin_amdgcn_s_setprio(1);
      {
        const char* vb = sVb + kh * 16384;
        bf16x8 pa = ld8(sPw + li * 64 + ((g * 16) ^ (((li >> 1) & 3) << 4)));
        #pragma unroll
        for (int nf = 0; nf < 16; ++nf) {
          int row = nf * 16 + li;
          bf16x8 vf = ld8(vb + row * 64 + ((g * 16) ^ (((row >> 1) & 3) << 4)));
          o_[nf] = __builtin_amdgcn_mfma_f32_16x16x32_bf16(pa, vf, o_[nf], 0, 0, 0);
        }
      }
      __builtin_amdgcn_s_setprio(0);

      asm volatile("s_barrier" ::: "memory");  // sV free for next tile
      if (more) asm volatile("s_waitcnt vmcnt(0)" ::: "memory");  // K(t+1) landed
      cur ^= 1;
    }

    // ---- unit merge: combine halves (kh=1 publishes; kh=0 merges + writes) ----
    if (kh == 1) {
      #pragma unroll
      for (int nf = 0; nf < 16; ++nf)
        *(f32x4*)(oex + wq * 4096 + nf * 256 + lane * 4) = o_[nf];
      #pragma unroll
      for (int r = 0; r < 4; ++r) {
        mlex[wq * 512 + r * 64 + lane] = l_[r];
        mlex[wq * 512 + 256 + r * 64 + lane] = m_[r];
      }
    }
    __syncthreads();
    if (kh == 0) {
      float aw[4], bw[4], inv_l[4];
      #pragma unroll
      for (int r = 0; r < 4; ++r) {
        float mB = mlex[wq * 512 + 256 + r * 64 + lane];
        float lB = mlex[wq * 512 + r * 64 + lane];
        float mm = fmaxf(m_[r], mB);
        aw[r] = __expf(m_[r] - mm);
        bw[r] = __expf(mB - mm);
        float lr = l_[r] * aw[r] + lB * bw[r];
        lr += __shfl_xor(lr, 1);
        lr += __shfl_xor(lr, 2);
        lr += __shfl_xor(lr, 4);
        lr += __shfl_xor(lr, 8);
        inv_l[r] = 1.0f / lr;
      }
      #pragma unroll
      for (int nf = 0; nf < 16; ++nf) {
        f32x4 ob = *(f32x4*)(oex + wq * 4096 + nf * 256 + lane * 4);
        #pragma unroll
        for (int r = 0; r < 4; ++r)
          o_[nf][r] = o_[nf][r] * aw[r] + ob[r] * bw[r];
      }
      // PMSNorm over d=256, *norm_weight, write merged bf16
      #pragma unroll
      for (int r = 0; r < 4; ++r) {
        float ss = 0.f;
        #pragma unroll
        for (int nf = 0; nf < 16; ++nf) {
          float v = o_[nf][r] * inv_l[r];
          ss += v * v;
        }
        ss += __shfl_xor(ss, 1);
        ss += __shfl_xor(ss, 2);
        ss += __shfl_xor(ss, 4);
        ss += __shfl_xor(ss, 8);
        float rms = rsqrtf(ss * (1.0f / 256.0f) + 1e-5f);
        int row = qt * 64 + wq * 16 + g * 4 + r;
        #pragma unroll
        for (int nf = 0; nf < 16; ++nf) {
          int d = nf * 16 + li;
          float v = o_[nf][r] * inv_l[r] * rms * nw[d];
          Mrg[((size_t)(b * 2048 + row)) * 2048 + h * 256 + d] = f2bf(v);
        }
      }
    }
    __syncthreads();  // oex/mlex (sK/sV) free before next unit's staging
  }
}

extern "C" void kernel_launch(void* const* d_in, const int* in_sizes, int n_in,
                              void* d_out, int out_size, void* d_ws, size_t ws_size,
                              hipStream_t stream) {
  const float* hs  = (const float*)d_in[0];   // [2,2048,2048]
  const float* wat = (const float*)d_in[1];   // [2048,6144]
  const float* wpr = (const float*)d_in[2];   // [2048,2048]
  const float* nw  = (const float*)d_in[3];   // [256]
  float* out = (float*)d_out;                 // [2,2048,2048] f32

  char* ws = (char*)d_ws;
  u16* Xb   = (u16*)(ws + 0);                    // 16 MiB  [4096][2048] bf16
  u16* Wp_t = (u16*)(ws + (16u << 20));          //  8 MiB  [2048][2048] bf16 (w_proj^T)
  u16* Qkv  = (u16*)(ws + (24u << 20));          // 48 MiB  [4096][6144] bf16
  u16* Vt   = (u16*)(ws + (72u << 20));          // 16 MiB  [16][256][2048] bf16
  u16* Mrg  = Xb;                                // aliases Xb (dead after GEMM1)
  u16* Wa_t = (u16*)d_out;                       // 24 MiB scratch (w_attn^T [6144][2048])

  dim3 t328(32, 8);
  cast_bf16_kernel<<<4096, 256, 0, stream>>>(hs, Xb, 1048576);
  tcast_kernel<<<dim3(192, 64), t328, 0, stream>>>(wat, Wa_t, 2048, 6144);
  tcast_kernel<<<dim3(64, 64), t328, 0, stream>>>(wpr, Wp_t, 2048, 2048);
  gemm_bt_kernel<<<dim3(48, 32), 256, 0, stream>>>(Xb, Wa_t, nullptr, Qkv, 4096, 6144, 2048);
  tv_kernel<<<dim3(8, 64, 16), t328, 0, stream>>>(Qkv, Vt);
  attn_kernel<<<256, 512, 0, stream>>>(Qkv, Vt, nw, Mrg);
  gemm_bt_kernel<<<dim3(16, 32), 256, 0, stream>>>(Mrg, Wp_t, out, nullptr, 4096, 2048, 2048);
  (void)in_sizes; (void)n_in; (void)out_size; (void)ws_size;
}